// Round 1
// baseline (616.113 us; speedup 1.0000x reference)
//
#include <hip/hip_runtime.h>

#define NN 8192
#define CC 512
#define DKK 64

typedef float f32x4 __attribute__((ext_vector_type(4)));
typedef _Float16 f16x8 __attribute__((ext_vector_type(8)));
typedef _Float16 f16x4 __attribute__((ext_vector_type(4)));

__device__ __forceinline__ f32x4 mfma16(f16x8 a, f16x8 b, f32x4 c) {
    return __builtin_amdgcn_mfma_f32_16x16x32_f16(a, b, c, 0, 0, 0);
}

// ---- transpose + f16-convert weights: W[512][Nout] f32 -> Wt[Nout][512] f16
__global__ void wtrans_kernel(const float* __restrict__ W, _Float16* __restrict__ Wt, int Nout) {
    int idx = blockIdx.x * 256 + threadIdx.x;
    if (idx >= Nout * 512) return;
    int n = idx >> 9;
    int k = idx & 511;
    Wt[idx] = (_Float16)W[k * Nout + n];
}

// ---- Q/K projection: X[N][512] f32 x Wt[64][512] -> O[N][64] f16 (row-major)
__global__ __launch_bounds__(256) void proj_qk_kernel(
    const float* __restrict__ im1, const float* __restrict__ im2,
    const _Float16* __restrict__ Wqt, const _Float16* __restrict__ Wkt,
    _Float16* __restrict__ Q1, _Float16* __restrict__ K1,
    _Float16* __restrict__ Q2, _Float16* __restrict__ K2)
{
    const float* X = blockIdx.y ? im2 : im1;
    const _Float16* Wt = blockIdx.z ? Wkt : Wqt;
    _Float16* O = blockIdx.y ? (blockIdx.z ? K2 : Q2) : (blockIdx.z ? K1 : Q1);
    const int lane = threadIdx.x & 63, wave = threadIdx.x >> 6;
    const int n16 = lane & 15, quad = lane >> 4;
    const int arow = blockIdx.x * 64 + wave * 16 + n16;

    f32x4 acc[4];
#pragma unroll
    for (int i = 0; i < 4; i++) acc[i] = (f32x4){0.f, 0.f, 0.f, 0.f};

    const float* xbase = X + (size_t)arow * 512 + quad * 8;
    for (int k0 = 0; k0 < 512; k0 += 32) {
        f32x4 xa = *(const f32x4*)(xbase + k0);
        f32x4 xb = *(const f32x4*)(xbase + k0 + 4);
        f16x8 a;
#pragma unroll
        for (int j = 0; j < 4; j++) { a[j] = (_Float16)xa[j]; a[4 + j] = (_Float16)xb[j]; }
#pragma unroll
        for (int t = 0; t < 4; t++) {
            f16x8 b = *(const f16x8*)(Wt + (size_t)(t * 16 + n16) * 512 + k0 + quad * 8);
            acc[t] = mfma16(a, b, acc[t]);
        }
    }
    const int rbase = blockIdx.x * 64 + wave * 16 + quad * 4;
#pragma unroll
    for (int t = 0; t < 4; t++)
#pragma unroll
        for (int r = 0; r < 4; r++)
            O[(size_t)(rbase + r) * 64 + t * 16 + n16] = (_Float16)acc[t][r];
}

// ---- V projection, transposed output: Vt[col][row] f16, Vt is [512][8192]
__global__ __launch_bounds__(256) void proj_v_kernel(
    const float* __restrict__ im1, const float* __restrict__ im2,
    const _Float16* __restrict__ Wvt,
    _Float16* __restrict__ V1t, _Float16* __restrict__ V2t)
{
    const float* X = blockIdx.z ? im2 : im1;
    _Float16* Vt = blockIdx.z ? V2t : V1t;
    const int cb = blockIdx.y * 64;
    const int lane = threadIdx.x & 63, wave = threadIdx.x >> 6;
    const int n16 = lane & 15, quad = lane >> 4;
    const int arow = blockIdx.x * 64 + wave * 16 + n16;

    f32x4 acc[4];
#pragma unroll
    for (int i = 0; i < 4; i++) acc[i] = (f32x4){0.f, 0.f, 0.f, 0.f};

    const float* xbase = X + (size_t)arow * 512 + quad * 8;
    for (int k0 = 0; k0 < 512; k0 += 32) {
        f32x4 xa = *(const f32x4*)(xbase + k0);
        f32x4 xb = *(const f32x4*)(xbase + k0 + 4);
        f16x8 a;
#pragma unroll
        for (int j = 0; j < 4; j++) { a[j] = (_Float16)xa[j]; a[4 + j] = (_Float16)xb[j]; }
#pragma unroll
        for (int t = 0; t < 4; t++) {
            f16x8 b = *(const f16x8*)(Wvt + (size_t)(cb + t * 16 + n16) * 512 + k0 + quad * 8);
            acc[t] = mfma16(a, b, acc[t]);
        }
    }
    const int rstore = blockIdx.x * 64 + wave * 16;
#pragma unroll
    for (int t = 0; t < 4; t++) {
        f16x4 v;
#pragma unroll
        for (int r = 0; r < 4; r++) v[r] = (_Float16)acc[t][r];
        *(f16x4*)(Vt + (size_t)(cb + t * 16 + n16) * NN + rstore + quad * 4) = v;
    }
}

// ---- fused flash cross-attention: out = softmax(Q K^T) @ V + resid
// grid (128, 2): x = q-tile of 64 rows, y = image. 512 threads = 8 waves:
// wave = (g rowgroup 0..3) * 2 + (h colhalf 0..1)
__global__ __launch_bounds__(512) void flash_kernel(
    const _Float16* __restrict__ Q1, const _Float16* __restrict__ K1,
    const _Float16* __restrict__ Q2, const _Float16* __restrict__ K2,
    const _Float16* __restrict__ V1t, const _Float16* __restrict__ V2t,
    const float* __restrict__ im1, const float* __restrict__ im2,
    float* __restrict__ out)
{
    const int img = blockIdx.y;
    // im1_out = softmax(im2_q @ im1_k^T) @ im1_v + im1
    const _Float16* Q = img ? Q1 : Q2;
    const _Float16* K = img ? K2 : K1;
    const _Float16* Vt = img ? V2t : V1t;
    const float* res = img ? im2 : im1;
    float* o = out + (size_t)img * NN * CC;

    __shared__ __align__(16) _Float16 Klds[64][72];   //  9 KB (pad 72 -> 2-way only)
    __shared__ __align__(16) _Float16 Vlds[512][72];  // 72 KB
    __shared__ __align__(16) _Float16 Plds[8][16][72];// 18 KB

    const int tid = threadIdx.x;
    const int lane = tid & 63, wave = tid >> 6;
    const int n16 = lane & 15, quad = lane >> 4;
    const int g = wave >> 1, h = wave & 1;

    const int qrow = blockIdx.x * 64 + g * 16 + n16;
    const f16x8 aq0 = *(const f16x8*)(Q + (size_t)qrow * DKK + quad * 8);
    const f16x8 aq1 = *(const f16x8*)(Q + (size_t)qrow * DKK + 32 + quad * 8);

    f32x4 acc[16];
#pragma unroll
    for (int i = 0; i < 16; i++) acc[i] = (f32x4){0.f, 0.f, 0.f, 0.f};
    float m_i[4], l_i[4];
#pragma unroll
    for (int r = 0; r < 4; r++) { m_i[r] = -1e30f; l_i[r] = 0.f; }

    const int sr = tid >> 3;        // 0..63
    const int sc = (tid & 7) * 8;   // 0..56

    for (int kv = 0; kv < NN; kv += 64) {
        // stage K tile [64][64] and V tile (transposed) [512][64] into LDS
        *(f16x8*)&Klds[sr][sc] = *(const f16x8*)(K + (size_t)(kv + sr) * DKK + sc);
#pragma unroll
        for (int p = 0; p < 8; p++) {
            int vr = p * 64 + sr;
            *(f16x8*)&Vlds[vr][sc] = *(const f16x8*)(Vt + (size_t)vr * NN + kv + sc);
        }
        __syncthreads();

        // S = Q K^T : 16 rows x 64 kv-cols per wave (dup x2 across col-halves)
        f32x4 s[4];
#pragma unroll
        for (int t = 0; t < 4; t++) {
            f16x8 b0 = *(const f16x8*)&Klds[t * 16 + n16][quad * 8];
            f16x8 b1 = *(const f16x8*)&Klds[t * 16 + n16][32 + quad * 8];
            f32x4 z = (f32x4){0.f, 0.f, 0.f, 0.f};
            z = mfma16(aq0, b0, z);
            z = mfma16(aq1, b1, z);
            s[t] = z;
        }

        // online softmax; lane owns rows quad*4+r, row lives in 16-lane group
        float mnew[4], alpha[4], rs[4];
#pragma unroll
        for (int r = 0; r < 4; r++) {
            float mx = fmaxf(fmaxf(s[0][r], s[1][r]), fmaxf(s[2][r], s[3][r]));
#pragma unroll
            for (int off = 8; off >= 1; off >>= 1)
                mx = fmaxf(mx, __shfl_xor(mx, off, 64));
            mnew[r] = fmaxf(m_i[r], mx);
            alpha[r] = __expf(m_i[r] - mnew[r]);
            m_i[r] = mnew[r];
            rs[r] = 0.f;
        }
#pragma unroll
        for (int t = 0; t < 4; t++) {
#pragma unroll
            for (int r = 0; r < 4; r++) {
                float p = __expf(s[t][r] - mnew[r]);
                rs[r] += p;
                Plds[wave][quad * 4 + r][t * 16 + n16] = (_Float16)p;
            }
        }
#pragma unroll
        for (int r = 0; r < 4; r++) {
            float v = rs[r];
#pragma unroll
            for (int off = 8; off >= 1; off >>= 1)
                v += __shfl_xor(v, off, 64);
            l_i[r] = l_i[r] * alpha[r] + v;
        }
#pragma unroll
        for (int t = 0; t < 16; t++)
#pragma unroll
            for (int r = 0; r < 4; r++)
                acc[t][r] *= alpha[r];

        // wave-level fence: P writes (C-layout) -> P reads (A-layout)
        asm volatile("s_waitcnt lgkmcnt(0)" ::: "memory");
        f16x8 pa0 = *(const f16x8*)&Plds[wave][n16][quad * 8];
        f16x8 pa1 = *(const f16x8*)&Plds[wave][n16][32 + quad * 8];

        // O += P @ V  (wave: 16 rows x 256 cols)
#pragma unroll
        for (int t = 0; t < 16; t++) {
            const int col = h * 256 + t * 16 + n16;
            f16x8 vb0 = *(const f16x8*)&Vlds[col][quad * 8];
            f16x8 vb1 = *(const f16x8*)&Vlds[col][32 + quad * 8];
            acc[t] = mfma16(pa0, vb0, acc[t]);
            acc[t] = mfma16(pa1, vb1, acc[t]);
        }
        __syncthreads();  // before next-iter staging overwrites K/V tiles
    }

    // epilogue: normalize, add residual, store fp32
    const int rbase = blockIdx.x * 64 + g * 16 + quad * 4;
#pragma unroll
    for (int r = 0; r < 4; r++) {
        const float inv = 1.f / l_i[r];
        const size_t rowoff = (size_t)(rbase + r) * CC;
#pragma unroll
        for (int t = 0; t < 16; t++) {
            const int col = h * 256 + t * 16 + n16;
            o[rowoff + col] = acc[t][r] * inv + res[rowoff + col];
        }
    }
}

extern "C" void kernel_launch(void* const* d_in, const int* in_sizes, int n_in,
                              void* d_out, int out_size, void* d_ws, size_t ws_size,
                              hipStream_t stream) {
    const float* im1 = (const float*)d_in[0];
    const float* im2 = (const float*)d_in[1];
    const float* Wq  = (const float*)d_in[2];
    const float* Wk  = (const float*)d_in[3];
    const float* Wv  = (const float*)d_in[4];
    float* out = (float*)d_out;

    _Float16* w = (_Float16*)d_ws;
    _Float16* Wqt = w;                      // 64*512
    _Float16* Wkt = Wqt + 64 * 512;         // 64*512
    _Float16* Wvt = Wkt + 64 * 512;         // 512*512
    _Float16* Q1  = Wvt + 512 * 512;        // 8192*64 each
    _Float16* K1  = Q1 + NN * DKK;
    _Float16* Q2  = K1 + NN * DKK;
    _Float16* K2  = Q2 + NN * DKK;
    _Float16* V1t = K2 + NN * DKK;          // 512*8192 each
    _Float16* V2t = V1t + (size_t)CC * NN;
    // total ~20.6 MB of ws

    wtrans_kernel<<<128, 256, 0, stream>>>(Wq, Wqt, 64);
    wtrans_kernel<<<128, 256, 0, stream>>>(Wk, Wkt, 64);
    wtrans_kernel<<<1024, 256, 0, stream>>>(Wv, Wvt, 512);
    proj_qk_kernel<<<dim3(128, 2, 2), 256, 0, stream>>>(im1, im2, Wqt, Wkt, Q1, K1, Q2, K2);
    proj_v_kernel<<<dim3(128, 8, 2), 256, 0, stream>>>(im1, im2, Wvt, V1t, V2t);
    flash_kernel<<<dim3(128, 2), 512, 0, stream>>>(Q1, K1, Q2, K2, V1t, V2t, im1, im2, out);
}